// Round 6
// baseline (179.699 us; speedup 1.0000x reference)
//
#include <hip/hip_runtime.h>
#include <stdint.h>
#include <stddef.h>

typedef __attribute__((ext_vector_type(8))) short s16x8;
typedef __attribute__((ext_vector_type(4))) short s16x4;
typedef __attribute__((ext_vector_type(4))) float f32x4;

#define B_  2
#define T_  2048
#define E_  1024
#define H_  16
#define E3_ 3072

// fp32 -> bf16, round-to-nearest-even
__device__ __forceinline__ short f2bf(float f) {
  union { float f; uint32_t u; } v; v.f = f;
  uint32_t u = v.u;
  return (short)((u + 0x7FFFu + ((u >> 16) & 1u)) >> 16);
}

__device__ __forceinline__ uint32_t fbits(float f) {
  union { float f; uint32_t u; } v; v.f = f; return v.u;
}

// async global->LDS, 16B per lane; lds dest = wave-uniform base + lane*16
__device__ __forceinline__ void gload_lds16(const short* g, short* l) {
  __builtin_amdgcn_global_load_lds(
      (__attribute__((address_space(1))) void*)(const_cast<short*>(g)),
      (__attribute__((address_space(3))) void*)(l), 16, 0, 0);
}

// ---------------- merged cast kernel (x, w_qkv, w_proj in one launch) -------
// Q-rows of w_qkv (first E rows) pre-scaled by log2(e)/8 so attention can
// call exp2f directly on MFMA output.
__global__ void castk_all(const float* __restrict__ x, const float* __restrict__ wqkv,
                          const float* __restrict__ wproj, short* __restrict__ xb,
                          short* __restrict__ wqkvb, short* __restrict__ wprojb) {
  const int bid = blockIdx.x;
  const float* in; short* out; int i; float sc = 1.0f;
  if (bid < 4096)      { in = x;     out = xb;     i = bid * 256 + threadIdx.x; }
  else if (bid < 7168) { in = wqkv;  out = wqkvb;  i = (bid - 4096) * 256 + threadIdx.x;
                         if (i < 262144) sc = 0.18033688011112042f; }
  else                 { in = wproj; out = wprojb; i = (bid - 7168) * 256 + threadIdx.x; }
  const float4 v = ((const float4*)in)[i];
  s16x4 o;
  o[0] = f2bf(v.x * sc); o[1] = f2bf(v.y * sc);
  o[2] = f2bf(v.z * sc); o[3] = f2bf(v.w * sc);
  ((s16x4*)out)[i] = o;
}

// ---------------- NT GEMM: C[M,N] = A[M,K] * B[N,K]^T (bf16 in, fp32 acc) ---
// MODE 0: fp32 output, plain. MODE 2: qkv mode — bf16 output; V columns
// (col >= 2E) are written TRANSPOSED into vt[b,h,d,t] (packed s16x4 over 4
// consecutive t), Q/K columns go to the qkv buffer. Fuses the old vtrans.
template <int MODE>
__global__ void gemm_nt_128(const short* __restrict__ A, const short* __restrict__ B,
                            void* __restrict__ Cv, short* __restrict__ vt,
                            int M, int N, int K) {
  __shared__ short As[128 * 32];
  __shared__ short Bs[128 * 32];
  const int tid  = threadIdx.x;
  const int lane = tid & 63;
  const int w    = tid >> 6;
  const int quad = lane >> 4;
  const int l16  = lane & 15;
  const int wm   = (w >> 1) * 64;
  const int wn   = (w & 1) * 64;
  const int bm   = blockIdx.y * 128;
  const int bn   = blockIdx.x * 128;

  f32x4 acc[4][4];
#pragma unroll
  for (int i = 0; i < 4; i++)
#pragma unroll
    for (int j = 0; j < 4; j++) acc[i][j] = (f32x4){0.f, 0.f, 0.f, 0.f};

  const int srow = w * 32 + (lane >> 2);
  const int scol = (lane & 3) * 8;
  const short* gA = A + (size_t)(bm + srow) * K + scol;
  const short* gB = B + (size_t)(bn + srow) * K + scol;
  short* lA = As + (w * 32) * 32;
  short* lB = Bs + (w * 32) * 32;

  for (int k0 = 0; k0 < K; k0 += 32) {
    __syncthreads();
    gload_lds16(gA + k0,          lA);
    gload_lds16(gA + 16 * K + k0, lA + 16 * 32);
    gload_lds16(gB + k0,          lB);
    gload_lds16(gB + 16 * K + k0, lB + 16 * 32);
    __syncthreads();

    s16x8 a[4], b[4];
#pragma unroll
    for (int i = 0; i < 4; i++)
      a[i] = *(const s16x8*)&As[(wm + i * 16 + l16) * 32 + quad * 8];
#pragma unroll
    for (int j = 0; j < 4; j++)
      b[j] = *(const s16x8*)&Bs[(wn + j * 16 + l16) * 32 + quad * 8];
#pragma unroll
    for (int i = 0; i < 4; i++)
#pragma unroll
      for (int j = 0; j < 4; j++)
        acc[i][j] = __builtin_amdgcn_mfma_f32_16x16x32_bf16(a[i], b[j], acc[i][j], 0, 0, 0);
  }

  if (MODE == 2 && bn >= 2 * E_) {
    // V block: write transposed to vt[b,h,d,t], 4 consecutive t per store
#pragma unroll
    for (int i = 0; i < 4; i++) {
      const int token = bm + wm + i * 16 + quad * 4;
      const int bb = token >> 11, t = token & (T_ - 1);
#pragma unroll
      for (int j = 0; j < 4; j++) {
        const int col = bn + wn + j * 16 + l16 - 2 * E_;  // h*64 + d
        s16x4 pk;
#pragma unroll
        for (int r = 0; r < 4; r++) pk[r] = f2bf(acc[i][j][r]);
        *(s16x4*)&vt[((size_t)(bb * H_ + (col >> 6)) * 64 + (col & 63)) * T_ + t] = pk;
      }
    }
  } else {
#pragma unroll
    for (int i = 0; i < 4; i++) {
      const int row0 = bm + wm + i * 16 + quad * 4;
#pragma unroll
      for (int j = 0; j < 4; j++) {
        const int col = bn + wn + j * 16 + l16;
#pragma unroll
        for (int r = 0; r < 4; r++) {
          const size_t idx = (size_t)(row0 + r) * N + col;
          if (MODE == 2) ((short*)Cv)[idx] = f2bf(acc[i][j][r]);
          else           ((float*)Cv)[idx] = acc[i][j][r];
        }
      }
    }
  }
}

// ---------------- flash attention -------------------------------------------
// 1024 blocks (one 64-row q-tile each), LPT-ordered: qt descending so the
// heavy blocks dispatch first and light ones backfill freed slots. LDS kept
// at exactly 40960 B -> 4 blocks/CU resident (4 waves/SIMD of latency
// hiding; rounds 4/5 never exceeded 2-3). S^T=K*Q^T C-layout packs P as b64;
// row sums via ones-MFMA; Q pre-scaled by log2e/8; diagonal-only masking;
// double-buffered K/V with stage issued before fragment reads; all swizzled
// LDS offsets hoisted to registers.
__global__ void __launch_bounds__(256, 4)
attn_kernel(const short* __restrict__ qkv, const short* __restrict__ vt,
            short* __restrict__ attout) {
  __shared__ short Ks[2][64 * 64];  // [kv][d], 16B-chunk swizzled
  __shared__ short Vs[2][64 * 64];  // [d][kv], 16B-chunk swizzled
  __shared__ short Ps[4][16 * 64];  // per-wave [q][kv], 16B-group swizzled
  const int tid  = threadIdx.x;
  const int lane = tid & 63;
  const int w    = tid >> 6;
  const int quad = lane >> 4;
  const int l16  = lane & 15;
  const int bh = blockIdx.x;
  const int b = bh >> 4, h = bh & 15;
  const int qt = 31 - (int)blockIdx.y;  // LPT: heavy first
  const int q0b = qt * 64;
  const int q0w = q0b + w * 16;
  const float NEG_INF = -__builtin_inff();

  const int srl = lane >> 3;
  const int sgc = ((lane & 7) ^ srl) * 8;
  const short* gK = qkv + (size_t)(b * T_) * E3_ + E_ + h * 64 + sgc;
  const short* gV = vt + (size_t)(bh * 64) * T_ + sgc;
  const int swz = (l16 & 7);

  // Q B-fragments (pre-scaled): B[n=l16][k=quad*8+j], two k-chunks
  const short* qbase = qkv + (size_t)(b * T_ + q0w + l16) * E3_ + h * 64 + quad * 8;
  const s16x8 qf0 = *(const s16x8*)(qbase);
  const s16x8 qf1 = *(const s16x8*)(qbase + 32);

  s16x8 ones;
#pragma unroll
  for (int i = 0; i < 8; i++) ones[i] = (short)0x3F80;  // bf16 1.0

  // hoisted LDS byte offsets (loop-invariant)
  int koff[2][4], pfoff[2], pwoff[4];
#pragma unroll
  for (int c = 0; c < 2; c++) {
#pragma unroll
    for (int j = 0; j < 4; j++)
      koff[c][j] = 2 * ((j * 16 + l16) * 64 + (((c * 4 + quad) ^ swz) * 8));
    pfoff[c] = 2 * (l16 * 64 + (((4 * c + quad) ^ swz) * 8));
  }
#pragma unroll
  for (int j = 0; j < 4; j++)
    pwoff[j] = 2 * (l16 * 64 + (((2 * j + (quad >> 1)) ^ swz) * 8) + (quad & 1) * 4);

  auto stage = [&](int kv0s, int bf) {
#pragma unroll
    for (int i = 0; i < 2; i++) {
      const int row = w * 16 + i * 8 + srl;
      gload_lds16(gK + (size_t)(kv0s + row) * E3_, &Ks[bf][(w * 16 + i * 8) * 64]);
      gload_lds16(gV + (size_t)row * T_ + kv0s,    &Vs[bf][(w * 16 + i * 8) * 64]);
    }
  };

  f32x4 o[4]; f32x4 ol = (f32x4){0.f, 0.f, 0.f, 0.f};
#pragma unroll
  for (int j = 0; j < 4; j++) o[j] = (f32x4){0.f, 0.f, 0.f, 0.f};

  // prologue: stage kv tile 0 into buffer 0
  stage(0, 0);
  __syncthreads();

  for (int kv0 = 0; kv0 <= q0b; kv0 += 64) {
    const int cur = (kv0 >> 6) & 1;

    // issue next tile's loads FIRST (they drain at this step's end barrier)
    if (kv0 + 64 <= q0b) stage(kv0 + 64, cur ^ 1);

    const char* kb = (const char*)&Ks[cur][0];
    const char* vb = (const char*)&Vs[cur][0];
    char* pb = (char*)&Ps[w][0];

    // K A-fragments for this step
    s16x8 kf[2][4];
#pragma unroll
    for (int c = 0; c < 2; c++)
#pragma unroll
      for (int j = 0; j < 4; j++)
        kf[c][j] = *(const s16x8*)(kb + koff[c][j]);

    // S^T tile: s[j][r] = score[kv = kv0+j*16+quad*4+r][q = q0w+l16]
    f32x4 s[4];
#pragma unroll
    for (int j = 0; j < 4; j++) s[j] = (f32x4){0.f, 0.f, 0.f, 0.f};
#pragma unroll
    for (int c = 0; c < 2; c++)
#pragma unroll
      for (int j = 0; j < 4; j++)
        s[j] = __builtin_amdgcn_mfma_f32_16x16x32_bf16(kf[c][j], c == 0 ? qf0 : qf1, s[j], 0, 0, 0);

    // mask only on the diagonal step
    if (kv0 == q0b) {
#pragma unroll
      for (int j = 0; j < 4; j++)
#pragma unroll
        for (int r = 0; r < 4; r++)
          if (j * 16 + quad * 4 + r > w * 16 + l16) s[j][r] = NEG_INF;
    }

    // exp2 + truncate-pack 4 consecutive kv -> one b64 (v_perm pack)
#pragma unroll
    for (int j = 0; j < 4; j++) {
      const float p0 = exp2f(s[j][0]);
      const float p1 = exp2f(s[j][1]);
      const float p2 = exp2f(s[j][2]);
      const float p3 = exp2f(s[j][3]);
      int2 pk;
      pk.x = (int)__builtin_amdgcn_perm(fbits(p1), fbits(p0), 0x07060302u);
      pk.y = (int)__builtin_amdgcn_perm(fbits(p3), fbits(p2), 0x07060302u);
      *(int2*)(pb + pwoff[j]) = pk;
    }
    // wave-private P: order writes vs cross-lane reads (LDS in-order per wave)
    __asm volatile("s_waitcnt lgkmcnt(0)" ::: "memory");

    // O += P V ; row sums via ones-MFMA (C-layout aligned with o[j])
#pragma unroll
    for (int c = 0; c < 2; c++) {
      const s16x8 pf = *(const s16x8*)(pb + pfoff[c]);
      ol = __builtin_amdgcn_mfma_f32_16x16x32_bf16(pf, ones, ol, 0, 0, 0);
#pragma unroll
      for (int j = 0; j < 4; j++) {
        const s16x8 vf = *(const s16x8*)(vb + koff[c][j]);
        o[j] = __builtin_amdgcn_mfma_f32_16x16x32_bf16(pf, vf, o[j], 0, 0, 0);
      }
    }

    __syncthreads();  // drains prefetch (covered by compute) + WAR fence
  }

  // epilogue: normalize by ol[r] (row sum, all lanes of the row identical)
#pragma unroll
  for (int r = 0; r < 4; r++) {
    const float inv = 1.0f / ol[r];
    const int q = q0w + quad * 4 + r;
    short* ob = attout + ((size_t)(b * T_ + q) * H_ + h) * 64 + l16;
    ob[0]  = f2bf(o[0][r] * inv);
    ob[16] = f2bf(o[1][r] * inv);
    ob[32] = f2bf(o[2][r] * inv);
    ob[48] = f2bf(o[3][r] * inv);
  }
}

// ---------------- launch -----------------------------------------------------
extern "C" void kernel_launch(void* const* d_in, const int* in_sizes, int n_in,
                              void* d_out, int out_size, void* d_ws, size_t ws_size,
                              hipStream_t stream) {
  const float* x     = (const float*)d_in[0];   // [4096, 1024] fp32
  const float* wqkv  = (const float*)d_in[1];   // [3072, 1024] fp32
  const float* wproj = (const float*)d_in[2];   // [1024, 1024] fp32

  if (ws_size < 58720256u) return;
  short* ws     = (short*)d_ws;
  short* xb     = ws;                    // 4096*1024
  short* wqkvb  = xb + 4194304;          // 3072*1024
  short* wprojb = wqkvb + 3145728;       // 1024*1024
  short* qkv    = wprojb + 1048576;      // 4096*3072 (V third unused)
  short* vt     = qkv + 12582912;        // 2*16*64*2048
  short* attb   = vt + 4194304;          // 4096*1024

  castk_all<<<8192, 256, 0, stream>>>(x, wqkv, wproj, xb, wqkvb, wprojb);
  gemm_nt_128<2><<<dim3(24, 32), 256, 0, stream>>>(xb, wqkvb, qkv, vt, 4096, 3072, 1024);
  attn_kernel<<<dim3(32, 32), 256, 0, stream>>>(qkv, vt, attb);
  gemm_nt_128<0><<<dim3(8, 32), 256, 0, stream>>>(attb, wprojb, d_out, nullptr, 4096, 1024, 1024);
}